// Round 1
// baseline (43.538 us; speedup 1.0000x reference)
//
#include <hip/hip_runtime.h>
#include <math.h>

#define EPS 1e-6f
#define LOG2E 1.4426950408889634f

constexpr int TB = 256;       // threads per block
constexpr int JCHUNK = 320;   // j's staged per block
constexpr int EPT = 4;        // edges per thread

// ---------------- dense pairwise term ----------------
// part[b] = sum over this block's (i,j) pairs of eg_i*eg_j*exp(-||z_i-z_j+eps||),
// with the diagonal contribution removed analytically.
__global__ void __launch_bounds__(TB) k_dense(
    const float2* __restrict__ Z, const float* __restrict__ gamma,
    float* __restrict__ part, int n, int nbj)
{
    __shared__ float4 sj[JCHUNK];
    const int bx = blockIdx.x;
    const int ib = bx / nbj, jb = bx % nbj;
    const int j0 = jb * JCHUNK;
    const int jn = min(JCHUNK, n - j0);

    for (int t = threadIdx.x; t < jn; t += TB) {
        float2 z = Z[j0 + t];
        sj[t] = make_float4(z.x, z.y, __expf(gamma[j0 + t]), 0.f);
    }
    __syncthreads();

    const int i = ib * TB + threadIdx.x;
    float acc = 0.f;
    if (i < n) {
        float2 zi = Z[i];
        const float ax = zi.x + EPS, ay = zi.y + EPS;
        #pragma unroll 4
        for (int t = 0; t < jn; ++t) {
            float4 s = sj[t];
            float dx = ax - s.x;
            float dy = ay - s.y;
            float r = __builtin_amdgcn_sqrtf(fmaf(dx, dx, dy * dy));
            acc = fmaf(s.z, __expf(-r), acc);
        }
        float egi = __expf(gamma[i]);
        if (i >= j0 && i < j0 + jn) {
            // remove diagonal term: dist_mat[i][i] = exp(-sqrt(2)*EPS)
            acc -= egi * __expf(-1.41421356e-6f);
        }
        acc *= egi;
    }

    // fixed-order block reduction (deterministic)
    for (int off = 32; off > 0; off >>= 1) acc += __shfl_down(acc, off, 64);
    __shared__ float wsum[TB / 64];
    const int lane = threadIdx.x & 63, w = threadIdx.x >> 6;
    if (lane == 0) wsum[w] = acc;
    __syncthreads();
    if (threadIdx.x == 0) {
        float s = 0.f;
        #pragma unroll
        for (int k = 0; k < TB / 64; ++k) s += wsum[k];
        part[bx] = s;
    }
}

// ---------------- sparse edge term ----------------
// part[b] = sum over this block's edges of (-||z_i-z_j+eps|| + gamma_i + gamma_j)
__global__ void __launch_bounds__(TB) k_edge(
    const float2* __restrict__ Z, const float* __restrict__ gamma,
    const int* __restrict__ ei, const int* __restrict__ ej,
    float* __restrict__ part, int e)
{
    const int base = blockIdx.x * TB * EPT + threadIdx.x;
    float acc = 0.f;
    #pragma unroll
    for (int k = 0; k < EPT; ++k) {
        int idx = base + k * TB;
        if (idx < e) {
            int a = ei[idx], b = ej[idx];
            float2 za = Z[a], zb = Z[b];
            float dx = za.x - zb.x + EPS;
            float dy = za.y - zb.y + EPS;
            float r = __builtin_amdgcn_sqrtf(fmaf(dx, dx, dy * dy));
            acc += gamma[a] + gamma[b] - r;
        }
    }
    for (int off = 32; off > 0; off >>= 1) acc += __shfl_down(acc, off, 64);
    __shared__ float wsum[TB / 64];
    const int lane = threadIdx.x & 63, w = threadIdx.x >> 6;
    if (lane == 0) wsum[w] = acc;
    __syncthreads();
    if (threadIdx.x == 0) {
        float s = 0.f;
        #pragma unroll
        for (int k = 0; k < TB / 64; ++k) s += wsum[k];
        part[blockIdx.x] = s;
    }
}

// ---------------- final reduction ----------------
// out[0] = edge_sum - 0.5 * dense_sum   (fp64, fixed tree order)
__global__ void __launch_bounds__(TB) k_final(
    const float* __restrict__ part_dense, int nd,
    const float* __restrict__ part_edge, int ne,
    float* __restrict__ out)
{
    double sd = 0.0, se = 0.0;
    for (int t = threadIdx.x; t < nd; t += TB) sd += (double)part_dense[t];
    for (int t = threadIdx.x; t < ne; t += TB) se += (double)part_edge[t];

    __shared__ double sh[TB];
    sh[threadIdx.x] = sd;
    __syncthreads();
    for (int s = TB / 2; s > 0; s >>= 1) {
        if (threadIdx.x < s) sh[threadIdx.x] += sh[threadIdx.x + s];
        __syncthreads();
    }
    double dense_sum = sh[0];
    __syncthreads();

    sh[threadIdx.x] = se;
    __syncthreads();
    for (int s = TB / 2; s > 0; s >>= 1) {
        if (threadIdx.x < s) sh[threadIdx.x] += sh[threadIdx.x + s];
        __syncthreads();
    }
    if (threadIdx.x == 0) {
        out[0] = (float)(sh[0] - 0.5 * dense_sum);
    }
}

extern "C" void kernel_launch(void* const* d_in, const int* in_sizes, int n_in,
                              void* d_out, int out_size, void* d_ws, size_t ws_size,
                              hipStream_t stream)
{
    const float2* Z     = (const float2*)d_in[0];
    const float*  gamma = (const float*)d_in[1];
    const int*    ei    = (const int*)d_in[2];
    const int*    ej    = (const int*)d_in[3];
    const int n = in_sizes[1];   // gamma length = N
    const int e = in_sizes[2];   // edge count = E
    float* out = (float*)d_out;

    const int nbj = (n + JCHUNK - 1) / JCHUNK;
    const int nbi = (n + TB - 1) / TB;
    const int nd  = nbi * nbj;
    const int ne  = (e + TB * EPT - 1) / (TB * EPT);

    float* part_dense = (float*)d_ws;
    float* part_edge  = part_dense + nd;

    hipLaunchKernelGGL(k_dense, dim3(nd), dim3(TB), 0, stream,
                       Z, gamma, part_dense, n, nbj);
    hipLaunchKernelGGL(k_edge, dim3(ne), dim3(TB), 0, stream,
                       Z, gamma, ei, ej, part_edge, e);
    hipLaunchKernelGGL(k_final, dim3(1), dim3(TB), 0, stream,
                       part_dense, nd, part_edge, ne, out);
}

// Round 2
// 32.473 us; speedup vs baseline: 1.3407x; 1.3407x over previous
//
#include <hip/hip_runtime.h>
#include <math.h>

#define EPS 1e-6f
#define LOG2E 1.4426950408889634f

constexpr int TDB = 128;   // dense tile dim & threads/block (2 waves)
constexpr int TEB = 256;   // edge block threads
constexpr int EPT = 4;     // edges per thread

// ---------------- dense pairwise term (triangular tiles) ----------------
// Exploits K_ij ~= K_ji (EPS asymmetry ~2.8e-6/pair, negligible vs 2% threshold).
// Block t covers tile-pair (a,b), b>=a. Off-diag tiles weighted x2; diag tiles
// computed full with the analytic diagonal exp(-sqrt(2)*EPS) removed.
// Coordinates are pre-scaled by log2(e) so the inner loop needs no multiply
// before v_exp: exp(-r) == exp2(-(log2e)*r) == exp2(-sqrt(((log2e)d)^2)).
__global__ void __launch_bounds__(TDB) k_dense(
    const float2* __restrict__ Z, const float* __restrict__ gamma,
    float* __restrict__ part, int n, int nb)
{
    __shared__ float4 sj[TDB];
    const int t = blockIdx.x;

    // decode triangular linear index -> (a, b) with b >= a
    auto before = [nb](int x) { return x * nb - (x * (x - 1)) / 2; };
    int a = (int)(((2 * nb + 1) -
                   sqrtf((float)((2 * nb + 1) * (2 * nb + 1) - 8 * t))) * 0.5f);
    if (a < 0) a = 0;
    if (a > nb - 1) a = nb - 1;
    while (before(a + 1) <= t) ++a;
    while (before(a) > t) --a;
    const int b = a + (t - before(a));

    const int j0 = b * TDB;
    const int jn = min(TDB, n - j0);

    if (threadIdx.x < jn) {
        const int j = j0 + threadIdx.x;
        float2 z = Z[j];
        sj[threadIdx.x] =
            make_float4(z.x * LOG2E, z.y * LOG2E, __expf(gamma[j]), 0.f);
    }
    __syncthreads();

    const int i = a * TDB + threadIdx.x;
    float acc = 0.f;
    if (i < n) {
        float2 zi = Z[i];
        const float ax = (zi.x + EPS) * LOG2E;
        const float ay = (zi.y + EPS) * LOG2E;
        #pragma unroll 8
        for (int k = 0; k < jn; ++k) {
            float4 s = sj[k];
            float dx = ax - s.x;
            float dy = ay - s.y;
            float r = __builtin_amdgcn_sqrtf(fmaf(dx, dx, dy * dy));
            acc = fmaf(s.z, __builtin_amdgcn_exp2f(-r), acc);
        }
        float egi = __expf(gamma[i]);
        if (a == b) acc -= egi * 0.9999985858f;   // exp(-sqrt(2)*EPS)
        acc *= egi;
    }

    // fixed-order deterministic block reduction
    for (int off = 32; off > 0; off >>= 1) acc += __shfl_down(acc, off, 64);
    __shared__ float wsum[TDB / 64];
    const int lane = threadIdx.x & 63, w = threadIdx.x >> 6;
    if (lane == 0) wsum[w] = acc;
    __syncthreads();
    if (threadIdx.x == 0) {
        float s = 0.f;
        #pragma unroll
        for (int k = 0; k < TDB / 64; ++k) s += wsum[k];
        part[t] = (a == b ? 1.f : 2.f) * s;
    }
}

// ---------------- sparse edge term ----------------
__global__ void __launch_bounds__(TEB) k_edge(
    const float2* __restrict__ Z, const float* __restrict__ gamma,
    const int* __restrict__ ei, const int* __restrict__ ej,
    float* __restrict__ part, int e)
{
    const int base = (blockIdx.x * TEB + threadIdx.x) * EPT;
    float acc = 0.f;
    if (base + EPT <= e) {
        int4 ia = *(const int4*)(ei + base);
        int4 ja = *(const int4*)(ej + base);
        const int as[EPT] = {ia.x, ia.y, ia.z, ia.w};
        const int bs[EPT] = {ja.x, ja.y, ja.z, ja.w};
        #pragma unroll
        for (int k = 0; k < EPT; ++k) {
            float2 za = Z[as[k]], zb = Z[bs[k]];
            float dx = za.x - zb.x + EPS;
            float dy = za.y - zb.y + EPS;
            float r = __builtin_amdgcn_sqrtf(fmaf(dx, dx, dy * dy));
            acc += gamma[as[k]] + gamma[bs[k]] - r;
        }
    } else {
        for (int k = 0; k < EPT; ++k) {
            int idx = base + k;
            if (idx < e) {
                int ai = ei[idx], bi = ej[idx];
                float2 za = Z[ai], zb = Z[bi];
                float dx = za.x - zb.x + EPS;
                float dy = za.y - zb.y + EPS;
                float r = __builtin_amdgcn_sqrtf(fmaf(dx, dx, dy * dy));
                acc += gamma[ai] + gamma[bi] - r;
            }
        }
    }
    for (int off = 32; off > 0; off >>= 1) acc += __shfl_down(acc, off, 64);
    __shared__ float wsum[TEB / 64];
    const int lane = threadIdx.x & 63, w = threadIdx.x >> 6;
    if (lane == 0) wsum[w] = acc;
    __syncthreads();
    if (threadIdx.x == 0) {
        float s = 0.f;
        #pragma unroll
        for (int k = 0; k < TEB / 64; ++k) s += wsum[k];
        part[blockIdx.x] = s;
    }
}

// ---------------- final reduction: out = edge - 0.5*dense ----------------
__global__ void __launch_bounds__(256) k_final(
    const float* __restrict__ part_dense, int nd,
    const float* __restrict__ part_edge, int ne,
    float* __restrict__ out)
{
    double sd = 0.0, se = 0.0;
    for (int t = threadIdx.x; t < nd; t += 256) sd += (double)part_dense[t];
    for (int t = threadIdx.x; t < ne; t += 256) se += (double)part_edge[t];

    __shared__ double sh[256];
    sh[threadIdx.x] = sd;
    __syncthreads();
    for (int s = 128; s > 0; s >>= 1) {
        if (threadIdx.x < s) sh[threadIdx.x] += sh[threadIdx.x + s];
        __syncthreads();
    }
    double dense_sum = sh[0];
    __syncthreads();

    sh[threadIdx.x] = se;
    __syncthreads();
    for (int s = 128; s > 0; s >>= 1) {
        if (threadIdx.x < s) sh[threadIdx.x] += sh[threadIdx.x + s];
        __syncthreads();
    }
    if (threadIdx.x == 0) out[0] = (float)(sh[0] - 0.5 * dense_sum);
}

extern "C" void kernel_launch(void* const* d_in, const int* in_sizes, int n_in,
                              void* d_out, int out_size, void* d_ws, size_t ws_size,
                              hipStream_t stream)
{
    const float2* Z     = (const float2*)d_in[0];
    const float*  gamma = (const float*)d_in[1];
    const int*    ei    = (const int*)d_in[2];
    const int*    ej    = (const int*)d_in[3];
    const int n = in_sizes[1];
    const int e = in_sizes[2];
    float* out = (float*)d_out;

    const int nb = (n + TDB - 1) / TDB;
    const int nd = nb * (nb + 1) / 2;
    const int ne = (e + TEB * EPT - 1) / (TEB * EPT);

    float* part_dense = (float*)d_ws;
    float* part_edge  = part_dense + nd;

    hipLaunchKernelGGL(k_dense, dim3(nd), dim3(TDB), 0, stream,
                       Z, gamma, part_dense, n, nb);
    hipLaunchKernelGGL(k_edge, dim3(ne), dim3(TEB), 0, stream,
                       Z, gamma, ei, ej, part_edge, e);
    hipLaunchKernelGGL(k_final, dim3(1), dim3(256), 0, stream,
                       part_dense, nd, part_edge, ne, out);
}

// Round 4
// 25.913 us; speedup vs baseline: 1.6801x; 1.2531x over previous
//
#include <hip/hip_runtime.h>
#include <math.h>

#define EPS 1e-6f
#define LOG2E 1.4426950408889634f

constexpr int TB  = 256;   // threads/block (4 waves) for all roles
constexpr int TD  = 256;   // dense tile dim (= TB: 1 i-row per thread, TD j's in LDS)
constexpr int EPT = 8;     // edges per thread

// Fused kernel. Blocks [0, nd): dense triangular tile-pairs.
// Blocks [nd, nd+ne): edge chunks.
// part[] is homogeneous: final answer = sum(part). Dense partials are stored
// pre-weighted by -0.5 (diag tile) or -1.0 (off-diag tile, counts (a,b)+(b,a));
// edge partials stored positive.
//
// Inner loop uses the DIFFERENCE form (d2 = dx*dx+dy*dy >= 0 structurally;
// the dot-product expansion cancels negative for near pairs -> sqrt(NaN),
// which is what sank R3). Coordinates pre-scaled by log2(e) so exp(-r) is a
// single v_exp_f32 with the free VOP3 negate: 4 full-rate + 2 trans per pair.
__global__ void __launch_bounds__(TB) k_fused(
    const float2* __restrict__ Z, const float* __restrict__ gamma,
    const int* __restrict__ ei, const int* __restrict__ ej,
    float* __restrict__ part, int n, int nb, int nd, int e)
{
    __shared__ float4 sj[TD];
    __shared__ float wsum[TB / 64];
    const int bx = blockIdx.x;
    float acc = 0.f;
    float blockw = 1.f;

    if (bx < nd) {
        // ---- dense role: decode triangular index -> (a,b), b >= a ----
        auto before = [nb](int x) { return x * nb - (x * (x - 1)) / 2; };
        int a = (int)(((2 * nb + 1) -
                       sqrtf((float)((2 * nb + 1) * (2 * nb + 1) - 8 * bx))) * 0.5f);
        if (a < 0) a = 0;
        if (a > nb - 1) a = nb - 1;
        while (before(a + 1) <= bx) ++a;
        while (before(a) > bx) --a;
        const int b = a + (bx - before(a));

        const int j0 = b * TD;
        const int jn = min(TD, n - j0);

        if (threadIdx.x < jn) {
            const int j = j0 + threadIdx.x;
            float2 z = Z[j];
            sj[threadIdx.x] = make_float4(z.x * LOG2E, z.y * LOG2E,
                                          __expf(gamma[j]), 0.f);
        }
        __syncthreads();

        const int i = a * TD + threadIdx.x;
        if (i < n) {
            float2 zi = Z[i];
            const float ax = (zi.x + EPS) * LOG2E;
            const float ay = (zi.y + EPS) * LOG2E;
            #pragma unroll 8
            for (int k = 0; k < jn; ++k) {
                float4 s = sj[k];
                float dx = ax - s.x;
                float dy = ay - s.y;
                float r = __builtin_amdgcn_sqrtf(fmaf(dx, dx, dy * dy));
                acc = fmaf(s.z, __builtin_amdgcn_exp2f(-r), acc);
            }
            float egi = __expf(gamma[i]);
            if (a == b) acc -= egi * 0.9999985858f;  // exp(-sqrt(2)*EPS)
            acc *= egi;
        }
        blockw = (a == b) ? -0.5f : -1.0f;
    } else {
        // ---- edge role ----
        const int c = bx - nd;
        const long base = ((long)c * TB + threadIdx.x) * EPT;
        if (base + EPT <= e) {
            int4 ia0 = *(const int4*)(ei + base);
            int4 ia1 = *(const int4*)(ei + base + 4);
            int4 ja0 = *(const int4*)(ej + base);
            int4 ja1 = *(const int4*)(ej + base + 4);
            const int as[EPT] = {ia0.x, ia0.y, ia0.z, ia0.w,
                                 ia1.x, ia1.y, ia1.z, ia1.w};
            const int bs[EPT] = {ja0.x, ja0.y, ja0.z, ja0.w,
                                 ja1.x, ja1.y, ja1.z, ja1.w};
            #pragma unroll
            for (int k = 0; k < EPT; ++k) {
                float2 za = Z[as[k]], zb = Z[bs[k]];
                float dx = za.x - zb.x + EPS;
                float dy = za.y - zb.y + EPS;
                float r = __builtin_amdgcn_sqrtf(fmaf(dx, dx, dy * dy));
                acc += gamma[as[k]] + gamma[bs[k]] - r;
            }
        } else {
            for (int k = 0; k < EPT; ++k) {
                long idx = base + k;
                if (idx < e) {
                    int ai = ei[idx], bi = ej[idx];
                    float2 za = Z[ai], zb = Z[bi];
                    float dx = za.x - zb.x + EPS;
                    float dy = za.y - zb.y + EPS;
                    float r = __builtin_amdgcn_sqrtf(fmaf(dx, dx, dy * dy));
                    acc += gamma[ai] + gamma[bi] - r;
                }
            }
        }
        blockw = 1.f;
    }

    // fixed-order deterministic block reduction
    for (int off = 32; off > 0; off >>= 1) acc += __shfl_down(acc, off, 64);
    const int lane = threadIdx.x & 63, w = threadIdx.x >> 6;
    if (lane == 0) wsum[w] = acc;
    __syncthreads();
    if (threadIdx.x == 0) {
        float s = 0.f;
        #pragma unroll
        for (int k = 0; k < TB / 64; ++k) s += wsum[k];
        part[bx] = blockw * s;
    }
}

// Final: out[0] = sum(part[0..np)) in fp64, fixed tree order.
__global__ void __launch_bounds__(256) k_final(
    const float* __restrict__ part, int np, float* __restrict__ out)
{
    double sd = 0.0;
    for (int t = threadIdx.x; t < np; t += 256) sd += (double)part[t];
    __shared__ double sh[256];
    sh[threadIdx.x] = sd;
    __syncthreads();
    for (int s = 128; s > 0; s >>= 1) {
        if (threadIdx.x < s) sh[threadIdx.x] += sh[threadIdx.x + s];
        __syncthreads();
    }
    if (threadIdx.x == 0) out[0] = (float)sh[0];
}

extern "C" void kernel_launch(void* const* d_in, const int* in_sizes, int n_in,
                              void* d_out, int out_size, void* d_ws, size_t ws_size,
                              hipStream_t stream)
{
    const float2* Z     = (const float2*)d_in[0];
    const float*  gamma = (const float*)d_in[1];
    const int*    ei    = (const int*)d_in[2];
    const int*    ej    = (const int*)d_in[3];
    const int n = in_sizes[1];
    const int e = in_sizes[2];
    float* out = (float*)d_out;

    const int nb = (n + TD - 1) / TD;
    const int nd = nb * (nb + 1) / 2;
    const int ne = (e + TB * EPT - 1) / (TB * EPT);
    const int np = nd + ne;

    float* part = (float*)d_ws;

    hipLaunchKernelGGL(k_fused, dim3(np), dim3(TB), 0, stream,
                       Z, gamma, ei, ej, part, n, nb, nd, e);
    hipLaunchKernelGGL(k_final, dim3(1), dim3(256), 0, stream,
                       part, np, out);
}